// Round 1
// baseline (358.125 us; speedup 1.0000x reference)
//
#include <hip/hip_runtime.h>
#include <math.h>

#define BB 2
#define TT 2048
#define DM 1024
#define NH 16
#define HS 64
#define MM (BB*TT)   // 4096

typedef __attribute__((ext_vector_type(8))) short s16x8;
typedef __attribute__((ext_vector_type(4))) float f32x4;

#define MFMA16(a,b,c) __builtin_amdgcn_mfma_f32_16x16x32_bf16((a),(b),(c),0,0,0)

__device__ inline unsigned short f2bf(float f) {
    union { float f; unsigned u; } x; x.f = f;
    unsigned r = x.u + 0x7fff + ((x.u >> 16) & 1);
    return (unsigned short)(r >> 16);
}

// ---------------------------------------------------------------------------
// Kernel 1: Q/K/V projection.  C[m, h*64+hs] = sum_d x[m,d] * W[h,d,hs]
// 64x64 output tile per block, 4 waves, each wave does 16 rows x 64 cols.
// ---------------------------------------------------------------------------
__global__ __launch_bounds__(256) void proj_qkv_kernel(
    const float* __restrict__ q, const float* __restrict__ k,
    const float* __restrict__ v,
    const float* __restrict__ Wq, const float* __restrict__ Wk,
    const float* __restrict__ Wv,
    unsigned short* __restrict__ Qb, unsigned short* __restrict__ Kb,
    unsigned short* __restrict__ Vb)
{
    __shared__ __align__(16) short As[64 * 56];
    __shared__ __align__(16) short Bs[64 * 56];

    const int tid = threadIdx.x;
    const int l = tid & 63, w = tid >> 6;
    const int m0 = blockIdx.y * 64;
    const int h  = blockIdx.x;            // n0 = h*64, one head per n-tile

    const float* x;  const float* W;  unsigned short* dst;
    if (blockIdx.z == 0)      { x = q; W = Wq; dst = Qb; }
    else if (blockIdx.z == 1) { x = k; W = Wk; dst = Kb; }
    else                      { x = v; W = Wv; dst = Vb; }
    const float* Wh = W + (size_t)h * DM * HS;

    f32x4 acc[4];
    for (int c = 0; c < 4; ++c)
        for (int j = 0; j < 4; ++j) acc[c][j] = 0.0f;

    const int arow = tid >> 2, acol = (tid & 3) * 8;   // A stage: 64 rows x 32 k
    const int bk = tid >> 3,  bn = (tid & 7) * 8;      // B stage: 32 k x 64 n

    for (int k0 = 0; k0 < DM; k0 += 32) {
        // stage A (fp32 -> bf16)
        const float* ap = x + (size_t)(m0 + arow) * DM + k0 + acol;
        float4 a0 = *(const float4*)ap;
        float4 a1 = *(const float4*)(ap + 4);
        s16x8 av;
        av[0] = (short)f2bf(a0.x); av[1] = (short)f2bf(a0.y);
        av[2] = (short)f2bf(a0.z); av[3] = (short)f2bf(a0.w);
        av[4] = (short)f2bf(a1.x); av[5] = (short)f2bf(a1.y);
        av[6] = (short)f2bf(a1.z); av[7] = (short)f2bf(a1.w);
        *(s16x8*)&As[arow * 56 + acol] = av;
        // stage B transposed: Bs[n][k] = W[k][n]
        const float* bp = Wh + (size_t)(k0 + bk) * HS + bn;
        float4 b0 = *(const float4*)bp;
        float4 b1 = *(const float4*)(bp + 4);
        float bfv[8] = {b0.x, b0.y, b0.z, b0.w, b1.x, b1.y, b1.z, b1.w};
        #pragma unroll
        for (int i = 0; i < 8; ++i)
            Bs[(bn + i) * 56 + bk] = (short)f2bf(bfv[i]);
        __syncthreads();
        // compute: wave w -> rows w*16..w*16+15, all 64 cols
        s16x8 afr = *(s16x8*)&As[(w * 16 + (l & 15)) * 56 + (l >> 4) * 8];
        #pragma unroll
        for (int c = 0; c < 4; ++c) {
            s16x8 bfr = *(s16x8*)&Bs[(c * 16 + (l & 15)) * 56 + (l >> 4) * 8];
            acc[c] = MFMA16(afr, bfr, acc[c]);
        }
        __syncthreads();
    }

    // epilogue: dst layout [B, H, T, HS]
    #pragma unroll
    for (int c = 0; c < 4; ++c)
        #pragma unroll
        for (int j = 0; j < 4; ++j) {
            int row = m0 + w * 16 + (l >> 4) * 4 + j;     // flat b*T+t
            int bb = row >> 11, tt = row & (TT - 1);
            int hs = c * 16 + (l & 15);
            dst[(((size_t)(bb * NH + h)) * TT + tt) * HS + hs] = f2bf(acc[c][j]);
        }
}

// ---------------------------------------------------------------------------
// Kernel 2: causal flash attention.  1 wave per (16 q-rows, b*h).
// Q,K,V bf16 [B,H,T,HS]; O bf16 [B,T,H*HS] (ready for out-proj).
// ---------------------------------------------------------------------------
__global__ __launch_bounds__(64) void flash_kernel(
    const unsigned short* __restrict__ Qb,
    const unsigned short* __restrict__ Kb,
    const unsigned short* __restrict__ Vb,
    unsigned short* __restrict__ Ob)
{
    __shared__ __align__(16) short Pl[16 * 56];

    const int l  = threadIdx.x;
    const int t0 = blockIdx.x * 16;
    const int bh = blockIdx.y;
    const int b = bh >> 4, h = bh & 15;
    const size_t base = (size_t)bh * TT * HS;
    const unsigned short* Qp = Qb + base;
    const unsigned short* Kp = Kb + base;
    const unsigned short* Vp = Vb + base;

    // Q fragments (A operand), rows t0..t0+15, K split in two 32-chunks
    s16x8 qf[2];
    #pragma unroll
    for (int s = 0; s < 2; ++s)
        qf[s] = *(const s16x8*)(Qp + (size_t)(t0 + (l & 15)) * HS + s * 32 + (l >> 4) * 8);

    float m_run[4], l_run[4];
    f32x4 o[4];
    #pragma unroll
    for (int j = 0; j < 4; ++j) { m_run[j] = -INFINITY; l_run[j] = 0.0f; }
    #pragma unroll
    for (int c = 0; c < 4; ++c)
        #pragma unroll
        for (int j = 0; j < 4; ++j) o[c][j] = 0.0f;

    for (int kv0 = 0; kv0 < t0 + 16; kv0 += 32) {
        // S = Q K^T  (two 16-col chunks)
        f32x4 sacc[2];
        #pragma unroll
        for (int c = 0; c < 2; ++c)
            #pragma unroll
            for (int j = 0; j < 4; ++j) sacc[c][j] = 0.0f;
        #pragma unroll
        for (int c = 0; c < 2; ++c)
            #pragma unroll
            for (int s = 0; s < 2; ++s) {
                // K rows loaded A-style == K^T as B operand
                s16x8 kf = *(const s16x8*)(Kp + (size_t)(kv0 + c * 16 + (l & 15)) * HS + s * 32 + (l >> 4) * 8);
                sacc[c] = MFMA16(qf[s], kf, sacc[c]);
            }

        // scale + causal mask + online softmax (rows live on 16-lane groups)
        float p[2][4], corr[4];
        #pragma unroll
        for (int j = 0; j < 4; ++j) {
            int rowg = t0 + (l >> 4) * 4 + j;
            #pragma unroll
            for (int c = 0; c < 2; ++c) {
                int colg = kv0 + c * 16 + (l & 15);
                float sv = sacc[c][j] * 0.125f;   // HS^-0.5 = 1/8
                p[c][j] = (colg <= rowg) ? sv : -INFINITY;
            }
            float pm = fmaxf(p[0][j], p[1][j]);
            #pragma unroll
            for (int off = 1; off < 16; off <<= 1)
                pm = fmaxf(pm, __shfl_xor(pm, off));
            float mn = fmaxf(m_run[j], pm);
            corr[j] = expf(m_run[j] - mn);
            m_run[j] = mn;
            p[0][j] = expf(p[0][j] - mn);
            p[1][j] = expf(p[1][j] - mn);
            float ps = p[0][j] + p[1][j];
            #pragma unroll
            for (int off = 1; off < 16; off <<= 1)
                ps += __shfl_xor(ps, off);
            l_run[j] = l_run[j] * corr[j] + ps;
        }
        #pragma unroll
        for (int c = 0; c < 4; ++c)
            #pragma unroll
            for (int j = 0; j < 4; ++j) o[c][j] *= corr[j];

        // P: D-layout -> A-layout via LDS
        __syncthreads();
        #pragma unroll
        for (int c = 0; c < 2; ++c)
            #pragma unroll
            for (int j = 0; j < 4; ++j)
                Pl[((l >> 4) * 4 + j) * 56 + c * 16 + (l & 15)] = (short)f2bf(p[c][j]);
        __syncthreads();
        s16x8 pa = *(s16x8*)&Pl[(l & 15) * 56 + (l >> 4) * 8];

        // O += P @ V  (V as B operand: column gather, 64B coalesced per row)
        #pragma unroll
        for (int c = 0; c < 4; ++c) {
            s16x8 vf;
            #pragma unroll
            for (int j2 = 0; j2 < 8; ++j2)
                vf[j2] = (short)Vp[(size_t)(kv0 + (l >> 4) * 8 + j2) * HS + c * 16 + (l & 15)];
            o[c] = MFMA16(pa, vf, o[c]);
        }
    }

    // write O / l   -> [B, T, H*HS]
    #pragma unroll
    for (int c = 0; c < 4; ++c)
        #pragma unroll
        for (int j = 0; j < 4; ++j) {
            int tt = t0 + (l >> 4) * 4 + j;
            float inv = 1.0f / l_run[j];
            Ob[((size_t)(b * TT + tt)) * DM + h * HS + c * 16 + (l & 15)] =
                f2bf(o[c][j] * inv);
        }
}

// ---------------------------------------------------------------------------
// Kernel 3: out = O @ Wo + bo   (fp32 out)
// ---------------------------------------------------------------------------
__global__ __launch_bounds__(256) void out_proj_kernel(
    const unsigned short* __restrict__ Ob, const float* __restrict__ Wo,
    const float* __restrict__ bo, float* __restrict__ out)
{
    __shared__ __align__(16) short As[64 * 56];
    __shared__ __align__(16) short Bs[64 * 56];

    const int tid = threadIdx.x;
    const int l = tid & 63, w = tid >> 6;
    const int m0 = blockIdx.y * 64;
    const int n0 = blockIdx.x * 64;

    f32x4 acc[4];
    for (int c = 0; c < 4; ++c)
        for (int j = 0; j < 4; ++j) acc[c][j] = 0.0f;

    const int arow = tid >> 2, acol = (tid & 3) * 8;
    const int bk = tid >> 3,  bn = (tid & 7) * 8;

    for (int k0 = 0; k0 < DM; k0 += 32) {
        // stage A (already bf16)
        s16x8 av = *(const s16x8*)(Ob + (size_t)(m0 + arow) * DM + k0 + acol);
        *(s16x8*)&As[arow * 56 + acol] = av;
        // stage B transposed
        const float* bp = Wo + (size_t)(k0 + bk) * DM + n0 + bn;
        float4 b0 = *(const float4*)bp;
        float4 b1 = *(const float4*)(bp + 4);
        float bfv[8] = {b0.x, b0.y, b0.z, b0.w, b1.x, b1.y, b1.z, b1.w};
        #pragma unroll
        for (int i = 0; i < 8; ++i)
            Bs[(bn + i) * 56 + bk] = (short)f2bf(bfv[i]);
        __syncthreads();
        s16x8 afr = *(s16x8*)&As[(w * 16 + (l & 15)) * 56 + (l >> 4) * 8];
        #pragma unroll
        for (int c = 0; c < 4; ++c) {
            s16x8 bfr = *(s16x8*)&Bs[(c * 16 + (l & 15)) * 56 + (l >> 4) * 8];
            acc[c] = MFMA16(afr, bfr, acc[c]);
        }
        __syncthreads();
    }

    #pragma unroll
    for (int c = 0; c < 4; ++c)
        #pragma unroll
        for (int j = 0; j < 4; ++j) {
            int row = m0 + w * 16 + (l >> 4) * 4 + j;
            int col = n0 + c * 16 + (l & 15);
            out[(size_t)row * DM + col] = acc[c][j] + bo[col];
        }
}

// ---------------------------------------------------------------------------
extern "C" void kernel_launch(void* const* d_in, const int* in_sizes, int n_in,
                              void* d_out, int out_size, void* d_ws, size_t ws_size,
                              hipStream_t stream) {
    const float* q  = (const float*)d_in[0];
    const float* k  = (const float*)d_in[1];
    const float* v  = (const float*)d_in[2];
    const float* Wq = (const float*)d_in[3];
    const float* Wk = (const float*)d_in[4];
    const float* Wv = (const float*)d_in[5];
    const float* Wo = (const float*)d_in[6];
    const float* bo = (const float*)d_in[7];
    float* out = (float*)d_out;

    const size_t QKV_ELEMS = (size_t)BB * NH * TT * HS;  // 4 Mi elems
    unsigned short* Qb = (unsigned short*)d_ws;
    unsigned short* Kb = Qb + QKV_ELEMS;
    unsigned short* Vb = Kb + QKV_ELEMS;
    unsigned short* Ob = Vb + QKV_ELEMS;                 // [M, D] bf16

    proj_qkv_kernel<<<dim3(NH, MM / 64, 3), 256, 0, stream>>>(
        q, k, v, Wq, Wk, Wv, Qb, Kb, Vb);
    flash_kernel<<<dim3(TT / 16, BB * NH), 64, 0, stream>>>(Qb, Kb, Vb, Ob);
    out_proj_kernel<<<dim3(DM / 64, MM / 64), 256, 0, stream>>>(Ob, Wo, bo, out);
}